// Round 3
// baseline (728.912 us; speedup 1.0000x reference)
//
#include <hip/hip_runtime.h>
#include <hip/hip_fp16.h>

// EMD approx-match (auction) + match_cost, fully fused, ONE normal launch.
// R17: R16 proved (a) cg grid.sync costs ~86us/sync (1175us total, VALUBusy
// 19%) due to system-scope L2 writeback/invalidate per block per sync; (b)
// cooperative launch is rejected under hipGraph capture (timed run fell back
// to 358us); (c) 1024 blocks @ 33.8KB LDS / 60 VGPR ARE co-resident (coop
// residency check passed, results correct). This round keeps the fusion but
// replaces the sync: hand-rolled per-batch barriers (8x128 blocks, monotonic
// round-up targets -> replay-safe; counters memset per launch) with relaxed
// agent-scope atomics + s_sleep(2) polling. NO cache-maintenance: all
// cross-block arrays (t1 triple-buffer, rr ping-pong, t9, out zeroing) are
// accessed exclusively through agent-scope atomic load/store (sc1 -> coherent
// point, bypasses stale per-XCD L2) or plain device-scope atomicAdd. Release
// ordering is free: __syncthreads drains vmcnt(0) before s_barrier, so all
// coherent writes are at the IF before the arrive-add.

#define BATCH 8
#define NPTS 2048
#define MPTS 2048
#define BLOCK 256
#define ROWS 16
#define BLOCKS_PER_BATCH 128
#define NSYNC 11
#define LOG2E 1.44269504088896340736f

__device__ __forceinline__ float fast_exp2(float x) {
  return __builtin_amdgcn_exp2f(x);     // v_exp_f32
}
__device__ __forceinline__ float fast_sqrt(float a) {
  return __builtin_amdgcn_sqrtf(a);     // v_sqrt_f32
}
__device__ __forceinline__ float packh2(float c, float r) {
  __half2 h = __halves2half2(__float2half_rn(c), __float2half_rn(r));
  return __builtin_bit_cast(float, h);
}

// ---- agent-scope coherent access helpers (bypass non-coherent XCD L2) ----
__device__ __forceinline__ float cohLoad(const float* p) {
  return __hip_atomic_load((float*)p, __ATOMIC_RELAXED,
                           __HIP_MEMORY_SCOPE_AGENT);
}
__device__ __forceinline__ void cohStore(float* p, float v) {
  __hip_atomic_store(p, v, __ATOMIC_RELAXED, __HIP_MEMORY_SCOPE_AGENT);
}
__device__ __forceinline__ float4 cohLoad4(const float4* p) {
  const float* f = (const float*)p;
  return make_float4(cohLoad(f), cohLoad(f + 1), cohLoad(f + 2),
                     cohLoad(f + 3));
}
__device__ __forceinline__ void cohStore4(float4* p, float4 v) {
  float* f = (float*)p;
  cohStore(f, v.x); cohStore(f + 1, v.y);
  cohStore(f + 2, v.z); cohStore(f + 3, v.w);
}

// Per-batch grid barrier. Monotonic round-up target: correct across graph
// replays (counter stays a multiple of 128 between launches; memset guards
// first-launch garbage). __syncthreads before arrive drains vmcnt(0) -> all
// this block's coherent writes are at the coherent point. Bounded spin: on
// residency failure we produce wrong results fast instead of hanging.
__device__ __forceinline__ void batch_barrier(unsigned* c) {
  __syncthreads();
  if (threadIdx.x == 0) {
    unsigned old = __hip_atomic_fetch_add(c, 1u, __ATOMIC_RELAXED,
                                          __HIP_MEMORY_SCOPE_AGENT);
    unsigned target = (old / BLOCKS_PER_BATCH + 1u) * BLOCKS_PER_BATCH;
    int guard = 0;
    while (__hip_atomic_load(c, __ATOMIC_RELAXED,
                             __HIP_MEMORY_SCOPE_AGENT) < target) {
      __builtin_amdgcn_s_sleep(2);
      if (++guard > (1 << 22)) break;
    }
  }
  asm volatile("" ::: "memory");
  __syncthreads();
}

// Load 8 consecutive points (r0 multiple of 8) as 6 float4s (raw).
__device__ __forceinline__ void load8(const float4* q, int r0,
                                      float* x, float* y, float* z) {
  int b4 = (r0 >> 2) * 3;
  float4 q0 = q[b4], q1 = q[b4 + 1], q2 = q[b4 + 2];
  float4 q3 = q[b4 + 3], q4 = q[b4 + 4], q5 = q[b4 + 5];
  x[0] = q0.x; y[0] = q0.y; z[0] = q0.z;
  x[1] = q0.w; y[1] = q1.x; z[1] = q1.y;
  x[2] = q1.z; y[2] = q1.w; z[2] = q2.x;
  x[3] = q2.y; y[3] = q2.z; z[3] = q2.w;
  x[4] = q3.x; y[4] = q3.y; z[4] = q3.z;
  x[5] = q3.w; y[5] = q4.x; z[5] = q4.y;
  x[6] = q4.z; y[6] = q4.w; z[6] = q5.x;
  x[7] = q5.y; y[7] = q5.z; z[7] = q5.w;
}

__global__ __launch_bounds__(BLOCK, 4) void emd_fused_kernel(
    const float* __restrict__ xyz1, const float* __restrict__ xyz2,
    float* __restrict__ out, float* __restrict__ t1b,
    float* __restrict__ rrA, float* __restrict__ rrB,
    float* __restrict__ t9, unsigned* __restrict__ ctr) {
  __shared__ float4 sP[MPTS];           // raw x2,y2,z2; w = per-level payload
  __shared__ float sRedS[ROWS * 4];
  __shared__ float sRedC[ROWS * 4];
  __shared__ float sRedR[ROWS * 4];
  __shared__ float sCost[ROWS];
  __shared__ float sRowScale[ROWS];     // persistent across levels
  __shared__ float sRemainL[ROWS];      // persistent across levels
  __shared__ float sRn[4];              // LAST-level sum(rn) partials

  const int tid = threadIdx.x;
  const int bid = blockIdx.x;
  const int b = bid >> 7;
  const int t0 = (bid & 127) * ROWS;
  const bool desig = (bid & 127) == 0;
  const int wave = tid >> 6, lane = tid & 63;
  const size_t bM = (size_t)b * MPTS;
  unsigned* cb = ctr + b;               // per-batch counters, stride BATCH

  float* cur = t1b + bM;
  float* nxt = t1b + (size_t)(BATCH * MPTS) + bM;
  float* zer = t1b + (size_t)(2 * BATCH * MPTS) + bM;
  float* rin = rrA + bM;
  float* rou = rrB + bM;

  const float4* q1 = (const float4*)(xyz1 + (size_t)b * NPTS * 3);
  const float4* q2 = (const float4*)(xyz2 + bM * 3);

  // ---- init: stage raw coords once; zero t1 buf0/buf1, out[b], t9[b] ----
  {
    float4* z0 = (float4*)cur;
    float4* z1 = (float4*)nxt;
    const float4 zz = make_float4(0.f, 0.f, 0.f, 0.f);
    for (int g = tid; g < MPTS / 4; g += BLOCK) {
      float4 a = q2[3 * g], bb = q2[3 * g + 1], c = q2[3 * g + 2];
      sP[4 * g + 0] = make_float4(a.x, a.y, a.z, 0.f);
      sP[4 * g + 1] = make_float4(a.w, bb.x, bb.y, 0.f);
      sP[4 * g + 2] = make_float4(bb.z, bb.w, c.x, 0.f);
      sP[4 * g + 3] = make_float4(c.y, c.z, c.w, 0.f);
      if (desig) { cohStore4(z0 + g, zz); cohStore4(z1 + g, zz); }
    }
    if (desig && tid == 0) { cohStore(out + b, 0.f); cohStore(t9 + b, 0.f); }
  }
  __syncthreads();

  // ---- A0: rowscale_0, then t1_0 accumulation ----
  const float nc0 = -16384.0f * LOG2E;
  {
    const int ph = lane >> 1, rg = lane & 1;
    float x1a[8], y1a[8], z1a[8], acc[8];
    load8(q1, t0 + rg * 8, x1a, y1a, z1a);
#pragma unroll
    for (int j = 0; j < 8; ++j) acc[j] = 0.f;
    const int mb = wave * 512 + ph;
#pragma unroll 2
    for (int it = 0; it < 16; ++it) {
      float4 v = sP[mb + it * 32];
#pragma unroll
      for (int j = 0; j < 8; ++j) {
        float dx = x1a[j] - v.x, dy = y1a[j] - v.y, dz = z1a[j] - v.z;
        float d2 = __builtin_fmaf(dx, dx, __builtin_fmaf(dy, dy, dz * dz));
        acc[j] += fast_exp2(nc0 * d2);
      }
    }
#pragma unroll
    for (int j = 0; j < 8; ++j) {
      acc[j] += __shfl_xor(acc[j], 2, 64);
      acc[j] += __shfl_xor(acc[j], 4, 64);
      acc[j] += __shfl_xor(acc[j], 8, 64);
      acc[j] += __shfl_xor(acc[j], 16, 64);
      acc[j] += __shfl_xor(acc[j], 32, 64);
    }
    if (lane < 2) {
#pragma unroll
      for (int j = 0; j < 8; ++j) sRedS[(rg * 8 + j) * 4 + wave] = acc[j];
    }
    __syncthreads();
    if (tid < ROWS) {
      float s = sRedS[tid * 4] + sRedS[tid * 4 + 1] + sRedS[tid * 4 + 2] +
                sRedS[tid * 4 + 3];
      sRowScale[tid] = 1.0f / (s + 1e-9f);
    }
    // barrier 0: t1 buf zeroes + out/t9 zeroes at coherent point before any
    // atomics; also the block barrier for sRowScale.
    batch_barrier(cb + 0 * BATCH);
    float rsn[8];
#pragma unroll
    for (int j = 0; j < 8; ++j) rsn[j] = sRowScale[rg * 8 + j];
#pragma unroll 2
    for (int it = 0; it < 16; ++it) {
      int idx = mb + it * 32;
      float4 v = sP[idx];
      float part = 0.f;
#pragma unroll
      for (int j = 0; j < 8; ++j) {
        float dx = x1a[j] - v.x, dy = y1a[j] - v.y, dz = z1a[j] - v.z;
        float d2 = __builtin_fmaf(dx, dx, __builtin_fmaf(dy, dy, dz * dz));
        part = __builtin_fmaf(fast_exp2(nc0 * d2), rsn[j], part);
      }
      part += __shfl_xor(part, 1, 64);
      if (rg == 0) atomicAdd(cur + idx, part);
    }
  }
  // barrier 1: t1_0 accumulation complete before level-0 staging reads it.
  batch_barrier(cb + 1 * BATCH);

  // ---- persistent CA row fragment (raw coords) ----
  float x1[4], y1[4], z1[4];
  {
    int b4 = ((t0 + (lane & 3) * 4) >> 2) * 3;
    float4 a = q1[b4], bb = q1[b4 + 1], c = q1[b4 + 2];
    x1[0] = a.x;  y1[0] = a.y;  z1[0] = a.z;
    x1[1] = a.w;  y1[1] = bb.x; z1[1] = bb.y;
    x1[2] = bb.z; y1[2] = bb.w; z1[2] = c.x;
    x1[3] = c.y;  y1[3] = c.z;  z1[3] = c.w;
  }
  const int phc = lane >> 2, rgc = lane & 3;
  const int mbc = wave * 512 + phc;

  float nc2 = -4096.0f * LOG2E;   // levels[l+1]*LOG2E; exact /4 per level
  for (int l = 0; l < 9; ++l) {
    const bool LAST = (l == 8);
    float rnsum = 0.f;
    {
      const float4* t14 = (const float4*)cur;
      const float4* rr4 = (const float4*)rin;
      float4* ro4 = (float4*)rou;
      float4* z4 = (float4*)zer;
      const float4 zz = make_float4(0.f, 0.f, 0.f, 0.f);
      for (int g = tid; g < MPTS / 4; g += BLOCK) {
        float4 t1v = cohLoad4(t14 + g);
        float4 rrv = (l == 0) ? make_float4(1.f, 1.f, 1.f, 1.f)
                              : cohLoad4(rr4 + g);
        float rrc[4] = {rrv.x, rrv.y, rrv.z, rrv.w};
        float t1c[4] = {t1v.x, t1v.y, t1v.z, t1v.w};
        float cc[4], rn[4];
#pragma unroll
        for (int i = 0; i < 4; ++i) {
          float colsum = rrc[i] * t1c[i];
          float cs = fminf(rrc[i] / (colsum + 1e-9f), 1.0f);
          cc[i] = rrc[i] * cs;
          rn[i] = fmaxf(rrc[i] - colsum * cs, 0.f);
        }
        rnsum += rn[0] + rn[1] + rn[2] + rn[3];
        sP[4 * g + 0].w = packh2(cc[0], rn[0]);
        sP[4 * g + 1].w = packh2(cc[1], rn[1]);
        sP[4 * g + 2].w = packh2(cc[2], rn[2]);
        sP[4 * g + 3].w = packh2(cc[3], rn[3]);
        if (desig) {
          cohStore4(ro4 + g, make_float4(rn[0], rn[1], rn[2], rn[3]));
          if (!LAST) cohStore4(z4 + g, zz);
        }
      }
      if (LAST) {   // R at last level = sum_m rn (e2 == 1)
        rnsum += __shfl_xor(rnsum, 1, 64);
        rnsum += __shfl_xor(rnsum, 2, 64);
        rnsum += __shfl_xor(rnsum, 4, 64);
        rnsum += __shfl_xor(rnsum, 8, 64);
        rnsum += __shfl_xor(rnsum, 16, 64);
        rnsum += __shfl_xor(rnsum, 32, 64);
        if (lane == 0) sRn[wave] = rnsum;
      }
    }
    __syncthreads();
    float accS[4] = {0.f, 0.f, 0.f, 0.f};
    float accC[4] = {0.f, 0.f, 0.f, 0.f};
    float accR[4] = {0.f, 0.f, 0.f, 0.f};
#pragma unroll 4
    for (int it = 0; it < 32; ++it) {
      float4 v = sP[mbc + it * 16];
      __half2 h = __builtin_bit_cast(__half2, v.w);
      float cc = __low2float(h);
      float rr = __high2float(h);
#pragma unroll
      for (int j = 0; j < 4; ++j) {
        float dx = x1[j] - v.x, dy = y1[j] - v.y, dz = z1[j] - v.z;
        float d2 = __builtin_fmaf(dx, dx, __builtin_fmaf(dy, dy, dz * dz));
        float sq = fast_sqrt(d2);
        float e2 = fast_exp2(nc2 * d2);
        float e2s = e2 * e2;
        float e1 = e2s * e2s;   // exp(levels[l]*d2); at LAST -> exp(-0.25 d2)
        float t = e1 * cc;
        accS[j] += t;
        accC[j] = __builtin_fmaf(t, sq, accC[j]);
        accR[j] = __builtin_fmaf(e2, rr, accR[j]);
      }
    }
#pragma unroll
    for (int j = 0; j < 4; ++j) {
      accS[j] += __shfl_xor(accS[j], 4, 64);
      accS[j] += __shfl_xor(accS[j], 8, 64);
      accS[j] += __shfl_xor(accS[j], 16, 64);
      accS[j] += __shfl_xor(accS[j], 32, 64);
      accC[j] += __shfl_xor(accC[j], 4, 64);
      accC[j] += __shfl_xor(accC[j], 8, 64);
      accC[j] += __shfl_xor(accC[j], 16, 64);
      accC[j] += __shfl_xor(accC[j], 32, 64);
      accR[j] += __shfl_xor(accR[j], 4, 64);
      accR[j] += __shfl_xor(accR[j], 8, 64);
      accR[j] += __shfl_xor(accR[j], 16, 64);
      accR[j] += __shfl_xor(accR[j], 32, 64);
    }
    if (lane < 4) {
#pragma unroll
      for (int j = 0; j < 4; ++j) {
        sRedS[(rgc * 4 + j) * 4 + wave] = accS[j];
        sRedC[(rgc * 4 + j) * 4 + wave] = accC[j];
        sRedR[(rgc * 4 + j) * 4 + wave] = accR[j];
      }
    }
    __syncthreads();
    if (tid < ROWS) {
      float S2 = sRedS[tid * 4] + sRedS[tid * 4 + 1] + sRedS[tid * 4 + 2] +
                 sRedS[tid * 4 + 3];
      float C = sRedC[tid * 4] + sRedC[tid * 4 + 1] + sRedC[tid * 4 + 2] +
                sRedC[tid * 4 + 3];
      float R = sRedR[tid * 4] + sRedR[tid * 4 + 1] + sRedR[tid * 4 + 2] +
                sRedR[tid * 4 + 3];
      if (LAST) R = sRn[0] + sRn[1] + sRn[2] + sRn[3];
      float rs = sRowScale[tid];
      float rl = (l == 0) ? 1.0f : sRemainL[tid];
      float rlN = fmaxf(rl - rs * S2, 0.f);
      sRemainL[tid] = rlN;
      sRowScale[tid] = rlN / (R + 1e-9f);
      sCost[tid] = rs * C;
    }
    __syncthreads();
    if (tid == 0) {
      float t = 0.f;
#pragma unroll
      for (int i = 0; i < ROWS; ++i) t += sCost[i];
      atomicAdd(out + b, t);
      if (LAST) {
        float r = 0.f;
#pragma unroll
        for (int i = 0; i < ROWS; ++i) r += sRowScale[i];
        atomicAdd(t9 + b, r);
      }
    }
    if (!LAST) {
      float rsn[4];
#pragma unroll
      for (int j = 0; j < 4; ++j) rsn[j] = sRowScale[rgc * 4 + j];
#pragma unroll 4
      for (int it = 0; it < 32; ++it) {
        int idx = mbc + it * 16;
        float4 v = sP[idx];
        float part = 0.f;
#pragma unroll
        for (int j = 0; j < 4; ++j) {
          float dx = x1[j] - v.x, dy = y1[j] - v.y, dz = z1[j] - v.z;
          float d2 = __builtin_fmaf(dx, dx, __builtin_fmaf(dy, dy, dz * dz));
          part = __builtin_fmaf(fast_exp2(nc2 * d2), rsn[j], part);
        }
        part += __shfl_xor(part, 1, 64);
        part += __shfl_xor(part, 2, 64);
        if (rgc == 0) atomicAdd(nxt + idx, part);
      }
    }
    // barrier 2+l: t1_{l+1} accumulation + rr_{l+1} stores complete.
    batch_barrier(cb + (2 + l) * BATCH);
    if (!LAST) {
      float* tp = cur; cur = nxt; nxt = zer; zer = tp;
      float* tr = rin; rin = rou; rou = tr;
      nc2 *= 0.25f;
    }
  }

  // ---- C9 (lvl=0): t1 scalar = t9[b]; cost with unscaled coords ----
  {
    const float t1 = cohLoad(t9 + b);
    const float4* rr4 = (const float4*)rou;   // rr_9 (no rotate at LAST)
    for (int g = tid; g < MPTS / 4; g += BLOCK) {
      float4 rr = cohLoad4(rr4 + g);
      sP[4 * g + 0].w = rr.x * fminf(rr.x / (__builtin_fmaf(rr.x, t1, 1e-9f)), 1.0f);
      sP[4 * g + 1].w = rr.y * fminf(rr.y / (__builtin_fmaf(rr.y, t1, 1e-9f)), 1.0f);
      sP[4 * g + 2].w = rr.z * fminf(rr.z / (__builtin_fmaf(rr.z, t1, 1e-9f)), 1.0f);
      sP[4 * g + 3].w = rr.w * fminf(rr.w / (__builtin_fmaf(rr.w, t1, 1e-9f)), 1.0f);
    }
    __syncthreads();
    const int ph = lane >> 1, rg = lane & 1;
    float x1a[8], y1a[8], z1a[8], acc[8];
    load8(q1, t0 + rg * 8, x1a, y1a, z1a);
#pragma unroll
    for (int j = 0; j < 8; ++j) acc[j] = 0.f;
    const int mb = wave * 512 + ph;
#pragma unroll 2
    for (int it = 0; it < 16; ++it) {
      float4 v = sP[mb + it * 32];
#pragma unroll
      for (int j = 0; j < 8; ++j) {
        float dx = x1a[j] - v.x, dy = y1a[j] - v.y, dz = z1a[j] - v.z;
        float d2 = __builtin_fmaf(dx, dx, __builtin_fmaf(dy, dy, dz * dz));
        acc[j] = __builtin_fmaf(fast_sqrt(d2), v.w, acc[j]);
      }
    }
#pragma unroll
    for (int j = 0; j < 8; ++j) {
      acc[j] += __shfl_xor(acc[j], 2, 64);
      acc[j] += __shfl_xor(acc[j], 4, 64);
      acc[j] += __shfl_xor(acc[j], 8, 64);
      acc[j] += __shfl_xor(acc[j], 16, 64);
      acc[j] += __shfl_xor(acc[j], 32, 64);
    }
    if (lane < 2) {
#pragma unroll
      for (int j = 0; j < 8; ++j) sRedS[(rg * 8 + j) * 4 + wave] = acc[j];
    }
    __syncthreads();
    if (tid < ROWS) {
      float C = sRedS[tid * 4] + sRedS[tid * 4 + 1] + sRedS[tid * 4 + 2] +
                sRedS[tid * 4 + 3];
      sCost[tid] = sRowScale[tid] * C;
    }
    __syncthreads();
    if (tid == 0) {
      float t = 0.f;
#pragma unroll
      for (int i = 0; i < ROWS; ++i) t += sCost[i];
      atomicAdd(out + b, t);
    }
  }
}

// ---------------------------------------------------------------------------
extern "C" void kernel_launch(void* const* d_in, const int* in_sizes, int n_in,
                              void* d_out, int out_size, void* d_ws, size_t ws_size,
                              hipStream_t stream) {
  const float* xyz1 = (const float*)d_in[0];
  const float* xyz2 = (const float*)d_in[1];
  float* out = (float*)d_out;
  float* ws = (float*)d_ws;

  const int BM = BATCH * MPTS;
  float* rrA = ws;                       // BM
  float* rrB = ws + BM;                  // BM
  float* t1b = ws + 2 * BM;              // 3*BM (triple buffer)
  float* t9  = ws + 5 * BM;              // BATCH (pad to 16)
  unsigned* ctr = (unsigned*)(ws + 5 * BM + 16);  // NSYNC*BATCH counters

  // zero barrier counters (keeps them multiples of 128 across graph replays)
  hipMemsetAsync(ctr, 0, NSYNC * BATCH * sizeof(unsigned), stream);

  void* args[] = {(void*)&xyz1, (void*)&xyz2, (void*)&out, (void*)&t1b,
                  (void*)&rrA, (void*)&rrB, (void*)&t9, (void*)&ctr};
  hipLaunchKernel((const void*)emd_fused_kernel,
                  dim3(BATCH * (NPTS / ROWS)), dim3(BLOCK), args, 0, stream);
}